// Round 6
// baseline (406.913 us; speedup 1.0000x reference)
//
#include <hip/hip_runtime.h>
#include <cstdint>
#include <cstddef>

// Problem constants
#define B_ 4
#define T_ 2048
#define C_ 1024
#define H_ 16
#define D_ 64
#define SCALE_ 0.125f

typedef _Float16 f16;
typedef f16 f16x4 __attribute__((ext_vector_type(4)));
typedef f16 f16x8 __attribute__((ext_vector_type(8)));
typedef float f32x4 __attribute__((ext_vector_type(4)));

// Async global->LDS 16B copy. LDS dest is wave-uniform base + lane*16.
__device__ __forceinline__ void async_ld16(const void* g, void* l) {
  __builtin_amdgcn_global_load_lds(
      (const __attribute__((address_space(1))) void*)g,
      (__attribute__((address_space(3))) void*)l,
      16, 0, 0);
}

// ---------------- merged prep: x cvt + two weight transposes (one dispatch) ------
__global__ void k_prep(const float* __restrict__ x, f16* __restrict__ xh,
                       const float* __restrict__ Wqkv, f16* __restrict__ WqkvT,
                       const float* __restrict__ Wout, f16* __restrict__ WoutT)
{
  __shared__ float tile[32][33];
  const int bx = blockIdx.x, t = threadIdx.x;
  if (bx < 8192) {
    int i = bx * 256 + t;
    float4 v = ((const float4*)x)[i];
    f16x4 h;
    h.x = (f16)v.x; h.y = (f16)v.y; h.z = (f16)v.z; h.w = (f16)v.w;
    ((f16x4*)xh)[i] = h;
    return;
  }
  const float* in; f16* out; int K, N, nt, kt;
  if (bx < 8192 + 3072) {
    int idx = bx - 8192; in = Wqkv; out = WqkvT; K = 1024; N = 3072;
    nt = idx % 96; kt = idx / 96;
  } else {
    int idx = bx - 11264; in = Wout; out = WoutT; K = 1024; N = 1024;
    nt = idx % 32; kt = idx / 32;
  }
  int tx = t & 31, ty = t >> 5;
  int k0 = kt * 32, n0 = nt * 32;
#pragma unroll
  for (int i = 0; i < 32; i += 8)
    tile[ty + i][tx] = in[(size_t)(k0 + ty + i) * N + n0 + tx];
  __syncthreads();
#pragma unroll
  for (int i = 0; i < 32; i += 8)
    out[(size_t)(n0 + ty + i) * K + k0 + tx] = (f16)tile[tx][ty + i];
}

// ---------------- streaming GEMM: C[M][N] = A[M][K] @ Bt^T, barrier-free ---------
// Round-6 restructure: no LDS, no __syncthreads in the K-loop. Each wave loads its
// MFMA fragments directly global->VGPR (per instr: 16 rows x 64 B = 16 full cache
// lines, coalesced in aggregate; A/B slices are L2-resident) with an explicit
// 2-stage register double-buffer. Removes the structural vmcnt(0)+s_barrier drain
// of the m97-style staged loop (m131-m141: tweaks on that structure are neutral).
// Epilogue: bias add; optional fused V-transpose (col>=2048 -> Vt[bh][d][t]) so
// the separate vtrans dispatch disappears.
// Registers: operands 4x4 f16x8 = 64 + acc 64 (AGPR) + addr/misc ~25 => fits the
// (256,3) 170-reg budget without spill.
__global__ __launch_bounds__(256, 3)
void k_gemm_bt(const f16* __restrict__ A, const f16* __restrict__ Bt,
               const float* __restrict__ bias, f16* __restrict__ Ch,
               float* __restrict__ Cf, f16* __restrict__ VtOut,
               int M, int N, int K)
{
  const int t = threadIdx.x;
  const int wave = t >> 6, lane = t & 63, lr = lane & 15, quad = lane >> 4;
  const int row0 = blockIdx.y * 128, col0 = blockIdx.x * 128;
  const int wm = (wave >> 1) * 64, wn = (wave & 1) * 64;

  const f16* pa = A  + (size_t)(row0 + wm + lr) * K + quad * 8;
  const f16* pb = Bt + (size_t)(col0 + wn + lr) * K + quad * 8;
  const size_t rs = (size_t)16 * K;   // 16-row stride in elements

  f32x4 acc[4][4] = {};
  f16x8 a0[4], b0[4], a1[4], b1[4];

#pragma unroll
  for (int i = 0; i < 4; ++i) {
    a0[i] = *(const f16x8*)(pa + i * rs);
    b0[i] = *(const f16x8*)(pb + i * rs);
  }

  for (int k0 = 0; k0 < K; k0 += 64) {
    // prefetch stage k0+32 (always in range: K multiple of 64)
#pragma unroll
    for (int i = 0; i < 4; ++i) {
      a1[i] = *(const f16x8*)(pa + i * rs + k0 + 32);
      b1[i] = *(const f16x8*)(pb + i * rs + k0 + 32);
    }
#pragma unroll
    for (int mi = 0; mi < 4; ++mi)
#pragma unroll
      for (int ni = 0; ni < 4; ++ni)
        acc[mi][ni] = __builtin_amdgcn_mfma_f32_16x16x32_f16(a0[mi], b0[ni], acc[mi][ni], 0, 0, 0);
    // prefetch stage k0+64
    if (k0 + 64 < K) {
#pragma unroll
      for (int i = 0; i < 4; ++i) {
        a0[i] = *(const f16x8*)(pa + i * rs + k0 + 64);
        b0[i] = *(const f16x8*)(pb + i * rs + k0 + 64);
      }
    }
#pragma unroll
    for (int mi = 0; mi < 4; ++mi)
#pragma unroll
      for (int ni = 0; ni < 4; ++ni)
        acc[mi][ni] = __builtin_amdgcn_mfma_f32_16x16x32_f16(a1[mi], b1[ni], acc[mi][ni], 0, 0, 0);
  }

  // epilogue: C/D layout col=lane&15, row=quad*4+reg
  if (VtOut != nullptr && col0 >= 2048) {
    // fused V transpose: QKV col c in [2048,3072) -> head h=(c-2048)>>6, d=(c-2048)&63
    // Vt[((b*16+h)*64 + d)*T + tt], tt = row & 2047, b = row >> 11
#pragma unroll
    for (int ni = 0; ni < 4; ++ni) {
      const int cb = col0 + wn + ni * 16 - 2048;   // cb%64 in {0,16,32,48}; +lr never crosses 64
      const int h = cb >> 6;
      const int dd = (cb & 63) + lr;
      const float bv = bias[2048 + cb + lr];
#pragma unroll
      for (int mi = 0; mi < 4; ++mi) {
#pragma unroll
        for (int r = 0; r < 4; ++r) {
          const int row = row0 + wm + mi * 16 + quad * 4 + r;
          const int bb = row >> 11, tt = row & 2047;
          VtOut[((size_t)(bb * 16 + h) * 64 + dd) * T_ + tt] = (f16)(acc[mi][ni][r] + bv);
        }
      }
    }
  } else {
#pragma unroll
    for (int mi = 0; mi < 4; ++mi) {
#pragma unroll
      for (int ni = 0; ni < 4; ++ni) {
        int col = col0 + wn + ni * 16 + lr;
        float bv = bias[col];
#pragma unroll
        for (int r = 0; r < 4; ++r) {
          int row = row0 + wm + mi * 16 + quad * 4 + r;
          float v = acc[mi][ni][r] + bv;
          if (Ch) Ch[(size_t)row * N + col] = (f16)v;
          else    Cf[(size_t)row * N + col] = v;
        }
      }
    }
  }
}

// ---------------- flash attention (causal), paired q-tiles, dbuf, swizzled LDS ----
// (unchanged from round 4)
__global__ __launch_bounds__(256, 4)
void k_flash(const f16* __restrict__ QKV, const f16* __restrict__ Vt, f16* __restrict__ O)
{
  __shared__ __align__(16) f16 Ks[2][64 * 64];
  __shared__ __align__(16) f16 Vs[2][64 * 64];
  __shared__ __align__(16) f16 Ps[4][16 * 64];

  const int a = blockIdx.x, bh = blockIdx.y;
  const int b = bh >> 4, h = bh & 15;
  const int qtA = a, qtB = 31 - a;     // qtA <= 15 < qtB
  const int t = threadIdx.x, wave = t >> 6, lane = t & 63, lr = lane & 15, quad = lane >> 4;
  const int lr3 = lr & 7;
  const int c0 = quad ^ lr3;           // swizzled chunk index for K/V k=quad*8
  const int c1 = c0 ^ 4;               // for k=32+quad*8

  const f16 scl = (f16)0.125f;
  const f16* qpA = QKV + (size_t)(b * T_ + qtA * 64 + wave * 16 + lr) * 3072 + h * 64;
  const f16* qpB = QKV + (size_t)(b * T_ + qtB * 64 + wave * 16 + lr) * 3072 + h * 64;
  f16x8 qA0 = *(const f16x8*)(qpA + quad * 8)      * scl;
  f16x8 qA1 = *(const f16x8*)(qpA + 32 + quad * 8) * scl;
  f16x8 qB0 = *(const f16x8*)(qpB + quad * 8)      * scl;
  f16x8 qB1 = *(const f16x8*)(qpB + 32 + quad * 8) * scl;

  float lA_[4] = {0.f, 0.f, 0.f, 0.f};
  float lB_[4] = {0.f, 0.f, 0.f, 0.f};
  f32x4 oA[4] = {}, oB[4] = {};

  const int sw = ((t & 7) ^ ((t >> 3) & 7)) * 8;
  const f16* gK = QKV + (size_t)(b * T_ + (t >> 3)) * 3072 + 1024 + h * 64 + sw;
  const f16* gV = Vt + ((size_t)bh * 64 + (t >> 3)) * T_ + sw;

  f16* myP = Ps[wave];
  f16* pw0 = myP + (quad * 4) * 64 + ((0 ^ quad) << 4) + lr;  // + r*64 (imm)
  f16* pw1 = myP + (quad * 4) * 64 + ((1 ^ quad) << 4) + lr;
  f16* pw2 = myP + (quad * 4) * 64 + ((2 ^ quad) << 4) + lr;
  f16* pw3 = myP + (quad * 4) * 64 + ((3 ^ quad) << 4) + lr;
  const f16* pr0 = myP + lr * 64 + ((((quad >> 1))     ^ (lr >> 2)) << 4) + ((quad & 1) << 3);
  const f16* pr1 = myP + lr * 64 + ((((quad >> 1) ^ 2) ^ (lr >> 2)) << 4) + ((quad & 1) << 3);

  const int last = qtB;

  {
    f16* lK = Ks[0] + wave * 512;
    f16* lV = Vs[0] + wave * 512;
    async_ld16(gK,                     lK);
    async_ld16(gK + (size_t)32 * 3072, lK + 2048);
    async_ld16(gV,                     lV);
    async_ld16(gV + (size_t)32 * T_,   lV + 2048);
  }

  for (int kt = 0; kt <= last; ++kt) {
    __syncthreads();
    const int buf = kt & 1;
    if (kt < last) {
      const f16* gk = gK + (size_t)((kt + 1) * 64) * 3072;
      const f16* gv = gV + (kt + 1) * 64;
      f16* lK = Ks[buf ^ 1] + wave * 512;
      f16* lV = Vs[buf ^ 1] + wave * 512;
      async_ld16(gk,                     lK);
      async_ld16(gk + (size_t)32 * 3072, lK + 2048);
      async_ld16(gv,                     lV);
      async_ld16(gv + (size_t)32 * T_,   lV + 2048);
    }
    const f16* K_ = Ks[buf];
    const f16* V_ = Vs[buf];
    const bool actA = (kt <= qtA);

    // ---- tile B ----
    {
      f32x4 s4[4];
#pragma unroll
      for (int ni = 0; ni < 4; ++ni) {
        const f16* kr = K_ + (ni * 16 + lr) * 64;
        f16x8 k0 = *(const f16x8*)(kr + c0 * 8);
        f16x8 k1 = *(const f16x8*)(kr + c1 * 8);
        f32x4 z = {};
        z = __builtin_amdgcn_mfma_f32_16x16x32_f16(qB0, k0, z, 0, 0, 0);
        z = __builtin_amdgcn_mfma_f32_16x16x32_f16(qB1, k1, z, 0, 0, 0);
        s4[ni] = z;
      }
      if (kt == qtB) {
        const int rloc = wave * 16 + quad * 4;
#pragma unroll
        for (int r = 0; r < 4; ++r) {
#pragma unroll
          for (int ni = 0; ni < 4; ++ni)
            if (ni * 16 + lr > rloc + r) s4[ni][r] = -1e30f;
        }
      }
#pragma unroll
      for (int r = 0; r < 4; ++r) {
        float e0 = __expf(s4[0][r]), e1 = __expf(s4[1][r]);
        float e2 = __expf(s4[2][r]), e3 = __expf(s4[3][r]);
        lB_[r] += (e0 + e1) + (e2 + e3);
        pw0[r * 64] = (f16)e0; pw1[r * 64] = (f16)e1;
        pw2[r * 64] = (f16)e2; pw3[r * 64] = (f16)e3;
      }
      f16x8 pB0 = *(const f16x8*)pr0;
      f16x8 pB1 = *(const f16x8*)pr1;
#pragma unroll
      for (int ni = 0; ni < 4; ++ni) {
        const f16* vr = V_ + (ni * 16 + lr) * 64;
        f16x8 v0 = *(const f16x8*)(vr + c0 * 8);
        f16x8 v1 = *(const f16x8*)(vr + c1 * 8);
        oB[ni] = __builtin_amdgcn_mfma_f32_16x16x32_f16(pB0, v0, oB[ni], 0, 0, 0);
        oB[ni] = __builtin_amdgcn_mfma_f32_16x16x32_f16(pB1, v1, oB[ni], 0, 0, 0);
      }
    }

    // ---- tile A ----
    if (actA) {
      f32x4 s4[4];
#pragma unroll
      for (int ni = 0; ni < 4; ++ni) {
        const f16* kr = K_ + (ni * 16 + lr) * 64;
        f16x8 k0 = *(const f16x8*)(kr + c0 * 8);
        f16x8 k1 = *(const f16x8*)(kr + c1 * 8);
        f32x4 z = {};
        z = __builtin_amdgcn_mfma_f32_16x16x32_f16(qA0, k0, z, 0, 0, 0);
        z = __builtin_amdgcn_mfma_f32_16x16x32_f16(qA1, k1, z, 0, 0, 0);
        s4[ni] = z;
      }
      if (kt == qtA) {
        const int rloc = wave * 16 + quad * 4;
#pragma unroll
        for (int r = 0; r < 4; ++r) {
#pragma unroll
          for (int ni = 0; ni < 4; ++ni)
            if (ni * 16 + lr > rloc + r) s4[ni][r] = -1e30f;
        }
      }
#pragma unroll
      for (int r = 0; r < 4; ++r) {
        float e0 = __expf(s4[0][r]), e1 = __expf(s4[1][r]);
        float e2 = __expf(s4[2][r]), e3 = __expf(s4[3][r]);
        lA_[r] += (e0 + e1) + (e2 + e3);
        pw0[r * 64] = (f16)e0; pw1[r * 64] = (f16)e1;
        pw2[r * 64] = (f16)e2; pw3[r * 64] = (f16)e3;
      }
      f16x8 pA0 = *(const f16x8*)pr0;
      f16x8 pA1 = *(const f16x8*)pr1;
#pragma unroll
      for (int ni = 0; ni < 4; ++ni) {
        const f16* vr = V_ + (ni * 16 + lr) * 64;
        f16x8 v0 = *(const f16x8*)(vr + c0 * 8);
        f16x8 v1 = *(const f16x8*)(vr + c1 * 8);
        oA[ni] = __builtin_amdgcn_mfma_f32_16x16x32_f16(pA0, v0, oA[ni], 0, 0, 0);
        oA[ni] = __builtin_amdgcn_mfma_f32_16x16x32_f16(pA1, v1, oA[ni], 0, 0, 0);
      }
    }
  }

  // epilogue: reduce l across the 16 lanes of each quad-group, normalize, store
#pragma unroll
  for (int r = 0; r < 4; ++r) {
    float la = lA_[r], lb = lB_[r];
#pragma unroll
    for (int off = 1; off < 16; off <<= 1) {
      la += __shfl_xor(la, off, 64);
      lb += __shfl_xor(lb, off, 64);
    }
    const int rowA = qtA * 64 + wave * 16 + quad * 4 + r;
    const int rowB = qtB * 64 + wave * 16 + quad * 4 + r;
    float invA = 1.f / la;
    float invB = 1.f / lb;
#pragma unroll
    for (int ni = 0; ni < 4; ++ni) {
      O[(size_t)(b * T_ + rowA) * C_ + h * 64 + ni * 16 + lr] = (f16)(oA[ni][r] * invA);
      O[(size_t)(b * T_ + rowB) * C_ + h * 64 + ni * 16 + lr] = (f16)(oB[ni][r] * invB);
    }
  }
}

// ---------------- launch ----------------
extern "C" void kernel_launch(void* const* d_in, const int* in_sizes, int n_in,
                              void* d_out, int out_size, void* d_ws, size_t ws_size,
                              hipStream_t stream)
{
  const float* x    = (const float*)d_in[0];
  const float* Wqkv = (const float*)d_in[1];
  const float* bqkv = (const float*)d_in[2];
  const float* Wout = (const float*)d_in[3];
  const float* bout = (const float*)d_in[4];
  float* out = (float*)d_out;

  f16* xh    = (f16*)d_ws;                            // 8192*1024
  f16* WqkvT = xh + (size_t)8192 * 1024;              // 3072*1024
  f16* WoutT = WqkvT + (size_t)3072 * 1024;           // 1024*1024
  f16* QKV   = WoutT + (size_t)1024 * 1024;           // 8192*3072 (V region unused)
  f16* VtG   = QKV + (size_t)8192 * 3072;             // 64*64*2048
  f16* Oh    = VtG + (size_t)64 * 64 * 2048;          // 8192*1024

  k_prep<<<12288, 256, 0, stream>>>(x, xh, Wqkv, WqkvT, Wout, WoutT);

  // QKV projection; V columns go directly (transposed) to VtG
  k_gemm_bt<<<dim3(3072 / 128, 8192 / 128), 256, 0, stream>>>(
      xh, WqkvT, bqkv, QKV, nullptr, VtG, 8192, 3072, 1024);

  k_flash<<<dim3(16, B_ * H_), 256, 0, stream>>>(QKV, VtG, Oh);

  // output projection -> f32 out
  k_gemm_bt<<<dim3(1024 / 128, 8192 / 128), 256, 0, stream>>>(
      Oh, WoutT, bout, nullptr, out, nullptr, 8192, 1024, 1024);
}

// Round 7
// 261.790 us; speedup vs baseline: 1.5544x; 1.5544x over previous
//
#include <hip/hip_runtime.h>
#include <cstdint>
#include <cstddef>

// Problem constants
#define B_ 4
#define T_ 2048
#define C_ 1024
#define H_ 16
#define D_ 64
#define SCALE_ 0.125f

typedef _Float16 f16;
typedef f16 f16x4 __attribute__((ext_vector_type(4)));
typedef f16 f16x8 __attribute__((ext_vector_type(8)));
typedef float f32x4 __attribute__((ext_vector_type(4)));

// Async global->LDS 16B copy. LDS dest is wave-uniform base + lane*16.
__device__ __forceinline__ void async_ld16(const void* g, void* l) {
  __builtin_amdgcn_global_load_lds(
      (const __attribute__((address_space(1))) void*)g,
      (__attribute__((address_space(3))) void*)l,
      16, 0, 0);
}

// ---------------- merged prep: x cvt + two weight transposes (one dispatch) ------
__global__ void k_prep(const float* __restrict__ x, f16* __restrict__ xh,
                       const float* __restrict__ Wqkv, f16* __restrict__ WqkvT,
                       const float* __restrict__ Wout, f16* __restrict__ WoutT)
{
  __shared__ float tile[32][33];
  const int bx = blockIdx.x, t = threadIdx.x;
  if (bx < 8192) {
    int i = bx * 256 + t;
    float4 v = ((const float4*)x)[i];
    f16x4 h;
    h.x = (f16)v.x; h.y = (f16)v.y; h.z = (f16)v.z; h.w = (f16)v.w;
    ((f16x4*)xh)[i] = h;
    return;
  }
  const float* in; f16* out; int K, N, nt, kt;
  if (bx < 8192 + 3072) {
    int idx = bx - 8192; in = Wqkv; out = WqkvT; K = 1024; N = 3072;
    nt = idx % 96; kt = idx / 96;
  } else {
    int idx = bx - 11264; in = Wout; out = WoutT; K = 1024; N = 1024;
    nt = idx % 32; kt = idx / 32;
  }
  int tx = t & 31, ty = t >> 5;
  int k0 = kt * 32, n0 = nt * 32;
#pragma unroll
  for (int i = 0; i < 32; i += 8)
    tile[ty + i][tx] = in[(size_t)(k0 + ty + i) * N + n0 + tx];
  __syncthreads();
#pragma unroll
  for (int i = 0; i < 32; i += 8)
    out[(size_t)(n0 + ty + i) * K + k0 + tx] = (f16)tile[tx][ty + i];
}

// ---------------- GEMM 256x128: C[M][N] = A[M][K] @ Bt^T ------------------------
// Round-7: proven m97-family LDS/dbuf structure (round-6's direct-global fragment
// loads were TA-bound: 16 cache lines per load instr -> MfmaUtil 10%), scaled to a
// 256x128 block tile: wave-tile 128x64, 12 ds_read_b128 per 32 MFMAs (1.33x more
// flops/LDS-byte than 128x128) and 2x flops per barrier. 768 blocks at 3/CU =
// exactly one co-resident round for the QKV GEMM. acc 128 + bf 16 + af 4 + addr
// ~= 165 regs, fits the (256,3) 170-reg budget. Fused V-transpose epilogue
// (col >= 2048 -> Vt[bh][d][t]) eliminates the separate vtrans dispatch.
__global__ __launch_bounds__(256, 3)
void k_gemm256(const f16* __restrict__ A, const f16* __restrict__ Bt,
               const float* __restrict__ bias, f16* __restrict__ Ch,
               f16* __restrict__ VtOut, int M, int N, int K)
{
  __shared__ __align__(16) f16 As[2][256 * 32];
  __shared__ __align__(16) f16 Bs[2][128 * 32];
  const int t = threadIdx.x;
  const int wave = t >> 6, lane = t & 63, lr = lane & 15, quad = lane >> 4;
  const int row0 = blockIdx.y * 256, col0 = blockIdx.x * 128;
  const int wm = (wave >> 1) * 128, wn = (wave & 1) * 64;

  f32x4 acc[8][4] = {};

  // staging: thread t -> rows (t>>2)+{0,64,128,192} (A) / +{0,64} (B), LDS chunk t&3;
  // source global chunk = (t&3) ^ ((row>>2)&3) = (t&3) ^ ((t>>4)&3)
  const int sw = ((t & 3) ^ ((t >> 4) & 3)) * 8;
  const f16* gA = A + (size_t)(row0 + (t >> 2)) * K + sw;
  const f16* gB = Bt + (size_t)(col0 + (t >> 2)) * K + sw;
  const size_t rowskip = (size_t)64 * K;
  // fragment read: LDS chunk = quad ^ ((row>>2)&3), row within 16-group = lr
  const int rc = (quad ^ (lr >> 2)) * 8;

  // prologue: stage k-chunk 0 into buf 0
  {
    f16* lA = As[0] + wave * 512;
    f16* lB = Bs[0] + wave * 512;
    async_ld16(gA,                lA);
    async_ld16(gA + rowskip,      lA + 2048);
    async_ld16(gA + 2 * rowskip,  lA + 4096);
    async_ld16(gA + 3 * rowskip,  lA + 6144);
    async_ld16(gB,                lB);
    async_ld16(gB + rowskip,      lB + 2048);
  }

  const int iters = K >> 5;
  for (int it = 0; it < iters; ++it) {
    __syncthreads();   // drains this buf's loads (issued last iter); guards buf^1 WAR
    const int buf = it & 1;
    if (it + 1 < iters) {
      const int k0 = (it + 1) * 32;
      f16* lA = As[buf ^ 1] + wave * 512;
      f16* lB = Bs[buf ^ 1] + wave * 512;
      async_ld16(gA + k0,               lA);
      async_ld16(gA + rowskip + k0,     lA + 2048);
      async_ld16(gA + 2 * rowskip + k0, lA + 4096);
      async_ld16(gA + 3 * rowskip + k0, lA + 6144);
      async_ld16(gB + k0,               lB);
      async_ld16(gB + rowskip + k0,     lB + 2048);
    }
    const f16* As_ = As[buf];
    const f16* Bs_ = Bs[buf];

    f16x8 bf[4];
#pragma unroll
    for (int i = 0; i < 4; ++i)
      bf[i] = *(const f16x8*)&Bs_[(wn + i * 16 + lr) * 32 + rc];
#pragma unroll
    for (int mi = 0; mi < 8; ++mi) {
      f16x8 af = *(const f16x8*)&As_[(wm + mi * 16 + lr) * 32 + rc];
#pragma unroll
      for (int ni = 0; ni < 4; ++ni)
        acc[mi][ni] = __builtin_amdgcn_mfma_f32_16x16x32_f16(af, bf[ni], acc[mi][ni], 0, 0, 0);
    }
  }

  // epilogue: C/D layout col=lane&15, row=quad*4+reg
  if (VtOut != nullptr && col0 >= 2048) {
    // fused V transpose: QKV col c in [2048,3072) -> h=(c-2048)>>6, d=(c-2048)&63
#pragma unroll
    for (int ni = 0; ni < 4; ++ni) {
      const int cb = col0 + wn + ni * 16 - 2048;   // cb%64 in {0,16,32,48}
      const int h = cb >> 6;
      const int dd = (cb & 63) + lr;
      const float bv = bias[2048 + cb + lr];
#pragma unroll
      for (int mi = 0; mi < 8; ++mi) {
#pragma unroll
        for (int r = 0; r < 4; ++r) {
          const int row = row0 + wm + mi * 16 + quad * 4 + r;
          const int bb = row >> 11, tt = row & 2047;
          VtOut[((size_t)(bb * 16 + h) * 64 + dd) * T_ + tt] = (f16)(acc[mi][ni][r] + bv);
        }
      }
    }
  } else {
#pragma unroll
    for (int mi = 0; mi < 8; ++mi) {
#pragma unroll
      for (int ni = 0; ni < 4; ++ni) {
        int col = col0 + wn + ni * 16 + lr;
        float bv = bias[col];
#pragma unroll
        for (int r = 0; r < 4; ++r) {
          int row = row0 + wm + mi * 16 + quad * 4 + r;
          Ch[(size_t)row * N + col] = (f16)(acc[mi][ni][r] + bv);
        }
      }
    }
  }
}

// ---------------- GEMM 128x128 (round-5 proven): for the output projection -------
__global__ __launch_bounds__(256, 3)
void k_gemm_bt(const f16* __restrict__ A, const f16* __restrict__ Bt,
               const float* __restrict__ bias, float* __restrict__ Cf,
               int M, int N, int K)
{
  __shared__ __align__(16) f16 As[2][128 * 32];
  __shared__ __align__(16) f16 Bs[2][128 * 32];
  const int t = threadIdx.x;
  const int wave = t >> 6, lane = t & 63, lr = lane & 15, quad = lane >> 4;
  const int row0 = blockIdx.y * 128, col0 = blockIdx.x * 128;
  const int wm = (wave >> 1) * 64, wn = (wave & 1) * 64;

  f32x4 acc[4][4] = {};

  const int sw = ((t & 3) ^ ((t >> 4) & 3)) * 8;
  const f16* gA = A + (size_t)(row0 + (t >> 2)) * K + sw;
  const f16* gB = Bt + (size_t)(col0 + (t >> 2)) * K + sw;
  const size_t rowskip = (size_t)64 * K;
  const int rc = (quad ^ (lr >> 2)) * 8;

  {
    f16* lA = As[0] + wave * 512;
    f16* lB = Bs[0] + wave * 512;
    async_ld16(gA,           lA);
    async_ld16(gA + rowskip, lA + 2048);
    async_ld16(gB,           lB);
    async_ld16(gB + rowskip, lB + 2048);
  }

  const int iters = K >> 5;
  for (int it = 0; it < iters; ++it) {
    __syncthreads();
    const int buf = it & 1;
    if (it + 1 < iters) {
      const int k0 = (it + 1) * 32;
      f16* lA = As[buf ^ 1] + wave * 512;
      f16* lB = Bs[buf ^ 1] + wave * 512;
      async_ld16(gA + k0,           lA);
      async_ld16(gA + rowskip + k0, lA + 2048);
      async_ld16(gB + k0,           lB);
      async_ld16(gB + rowskip + k0, lB + 2048);
    }
    const f16* As_ = As[buf];
    const f16* Bs_ = Bs[buf];

    f16x8 af[4], bf[4];
#pragma unroll
    for (int i = 0; i < 4; ++i) {
      af[i] = *(const f16x8*)&As_[(wm + i * 16 + lr) * 32 + rc];
      bf[i] = *(const f16x8*)&Bs_[(wn + i * 16 + lr) * 32 + rc];
    }
#pragma unroll
    for (int mi = 0; mi < 4; ++mi)
#pragma unroll
      for (int ni = 0; ni < 4; ++ni)
        acc[mi][ni] = __builtin_amdgcn_mfma_f32_16x16x32_f16(af[mi], bf[ni], acc[mi][ni], 0, 0, 0);
  }

#pragma unroll
  for (int mi = 0; mi < 4; ++mi) {
#pragma unroll
    for (int ni = 0; ni < 4; ++ni) {
      int col = col0 + wn + ni * 16 + lr;
      float bv = bias[col];
#pragma unroll
      for (int r = 0; r < 4; ++r) {
        int row = row0 + wm + mi * 16 + quad * 4 + r;
        Cf[(size_t)row * N + col] = acc[mi][ni][r] + bv;
      }
    }
  }
}

// ---------------- flash attention (causal), paired q-tiles, dbuf, swizzled LDS ----
// (unchanged from round 4)
__global__ __launch_bounds__(256, 4)
void k_flash(const f16* __restrict__ QKV, const f16* __restrict__ Vt, f16* __restrict__ O)
{
  __shared__ __align__(16) f16 Ks[2][64 * 64];
  __shared__ __align__(16) f16 Vs[2][64 * 64];
  __shared__ __align__(16) f16 Ps[4][16 * 64];

  const int a = blockIdx.x, bh = blockIdx.y;
  const int b = bh >> 4, h = bh & 15;
  const int qtA = a, qtB = 31 - a;     // qtA <= 15 < qtB
  const int t = threadIdx.x, wave = t >> 6, lane = t & 63, lr = lane & 15, quad = lane >> 4;
  const int lr3 = lr & 7;
  const int c0 = quad ^ lr3;           // swizzled chunk index for K/V k=quad*8
  const int c1 = c0 ^ 4;               // for k=32+quad*8

  const f16 scl = (f16)0.125f;
  const f16* qpA = QKV + (size_t)(b * T_ + qtA * 64 + wave * 16 + lr) * 3072 + h * 64;
  const f16* qpB = QKV + (size_t)(b * T_ + qtB * 64 + wave * 16 + lr) * 3072 + h * 64;
  f16x8 qA0 = *(const f16x8*)(qpA + quad * 8)      * scl;
  f16x8 qA1 = *(const f16x8*)(qpA + 32 + quad * 8) * scl;
  f16x8 qB0 = *(const f16x8*)(qpB + quad * 8)      * scl;
  f16x8 qB1 = *(const f16x8*)(qpB + 32 + quad * 8) * scl;

  float lA_[4] = {0.f, 0.f, 0.f, 0.f};
  float lB_[4] = {0.f, 0.f, 0.f, 0.f};
  f32x4 oA[4] = {}, oB[4] = {};

  const int sw = ((t & 7) ^ ((t >> 3) & 7)) * 8;
  const f16* gK = QKV + (size_t)(b * T_ + (t >> 3)) * 3072 + 1024 + h * 64 + sw;
  const f16* gV = Vt + ((size_t)bh * 64 + (t >> 3)) * T_ + sw;

  f16* myP = Ps[wave];
  f16* pw0 = myP + (quad * 4) * 64 + ((0 ^ quad) << 4) + lr;  // + r*64 (imm)
  f16* pw1 = myP + (quad * 4) * 64 + ((1 ^ quad) << 4) + lr;
  f16* pw2 = myP + (quad * 4) * 64 + ((2 ^ quad) << 4) + lr;
  f16* pw3 = myP + (quad * 4) * 64 + ((3 ^ quad) << 4) + lr;
  const f16* pr0 = myP + lr * 64 + ((((quad >> 1))     ^ (lr >> 2)) << 4) + ((quad & 1) << 3);
  const f16* pr1 = myP + lr * 64 + ((((quad >> 1) ^ 2) ^ (lr >> 2)) << 4) + ((quad & 1) << 3);

  const int last = qtB;

  {
    f16* lK = Ks[0] + wave * 512;
    f16* lV = Vs[0] + wave * 512;
    async_ld16(gK,                     lK);
    async_ld16(gK + (size_t)32 * 3072, lK + 2048);
    async_ld16(gV,                     lV);
    async_ld16(gV + (size_t)32 * T_,   lV + 2048);
  }

  for (int kt = 0; kt <= last; ++kt) {
    __syncthreads();
    const int buf = kt & 1;
    if (kt < last) {
      const f16* gk = gK + (size_t)((kt + 1) * 64) * 3072;
      const f16* gv = gV + (kt + 1) * 64;
      f16* lK = Ks[buf ^ 1] + wave * 512;
      f16* lV = Vs[buf ^ 1] + wave * 512;
      async_ld16(gk,                     lK);
      async_ld16(gk + (size_t)32 * 3072, lK + 2048);
      async_ld16(gv,                     lV);
      async_ld16(gv + (size_t)32 * T_,   lV + 2048);
    }
    const f16* K_ = Ks[buf];
    const f16* V_ = Vs[buf];
    const bool actA = (kt <= qtA);

    // ---- tile B ----
    {
      f32x4 s4[4];
#pragma unroll
      for (int ni = 0; ni < 4; ++ni) {
        const f16* kr = K_ + (ni * 16 + lr) * 64;
        f16x8 k0 = *(const f16x8*)(kr + c0 * 8);
        f16x8 k1 = *(const f16x8*)(kr + c1 * 8);
        f32x4 z = {};
        z = __builtin_amdgcn_mfma_f32_16x16x32_f16(qB0, k0, z, 0, 0, 0);
        z = __builtin_amdgcn_mfma_f32_16x16x32_f16(qB1, k1, z, 0, 0, 0);
        s4[ni] = z;
      }
      if (kt == qtB) {
        const int rloc = wave * 16 + quad * 4;
#pragma unroll
        for (int r = 0; r < 4; ++r) {
#pragma unroll
          for (int ni = 0; ni < 4; ++ni)
            if (ni * 16 + lr > rloc + r) s4[ni][r] = -1e30f;
        }
      }
#pragma unroll
      for (int r = 0; r < 4; ++r) {
        float e0 = __expf(s4[0][r]), e1 = __expf(s4[1][r]);
        float e2 = __expf(s4[2][r]), e3 = __expf(s4[3][r]);
        lB_[r] += (e0 + e1) + (e2 + e3);
        pw0[r * 64] = (f16)e0; pw1[r * 64] = (f16)e1;
        pw2[r * 64] = (f16)e2; pw3[r * 64] = (f16)e3;
      }
      f16x8 pB0 = *(const f16x8*)pr0;
      f16x8 pB1 = *(const f16x8*)pr1;
#pragma unroll
      for (int ni = 0; ni < 4; ++ni) {
        const f16* vr = V_ + (ni * 16 + lr) * 64;
        f16x8 v0 = *(const f16x8*)(vr + c0 * 8);
        f16x8 v1 = *(const f16x8*)(vr + c1 * 8);
        oB[ni] = __builtin_amdgcn_mfma_f32_16x16x32_f16(pB0, v0, oB[ni], 0, 0, 0);
        oB[ni] = __builtin_amdgcn_mfma_f32_16x16x32_f16(pB1, v1, oB[ni], 0, 0, 0);
      }
    }

    // ---- tile A ----
    if (actA) {
      f32x4 s4[4];
#pragma unroll
      for (int ni = 0; ni < 4; ++ni) {
        const f16* kr = K_ + (ni * 16 + lr) * 64;
        f16x8 k0 = *(const f16x8*)(kr + c0 * 8);
        f16x8 k1 = *(const f16x8*)(kr + c1 * 8);
        f32x4 z = {};
        z = __builtin_amdgcn_mfma_f32_16x16x32_f16(qA0, k0, z, 0, 0, 0);
        z = __builtin_amdgcn_mfma_f32_16x16x32_f16(qA1, k1, z, 0, 0, 0);
        s4[ni] = z;
      }
      if (kt == qtA) {
        const int rloc = wave * 16 + quad * 4;
#pragma unroll
        for (int r = 0; r < 4; ++r) {
#pragma unroll
          for (int ni = 0; ni < 4; ++ni)
            if (ni * 16 + lr > rloc + r) s4[ni][r] = -1e30f;
        }
      }
#pragma unroll
      for (int r = 0; r < 4; ++r) {
        float e0 = __expf(s4[0][r]), e1 = __expf(s4[1][r]);
        float e2 = __expf(s4[2][r]), e3 = __expf(s4[3][r]);
        lA_[r] += (e0 + e1) + (e2 + e3);
        pw0[r * 64] = (f16)e0; pw1[r * 64] = (f16)e1;
        pw2[r * 64] = (f16)e2; pw3[r * 64] = (f16)e3;
      }
      f16x8 pA0 = *(const f16x8*)pr0;
      f16x8 pA1 = *(const f16x8*)pr1;
#pragma unroll
      for (int ni = 0; ni < 4; ++ni) {
        const f16* vr = V_ + (ni * 16 + lr) * 64;
        f16x8 v0 = *(const f16x8*)(vr + c0 * 8);
        f16x8 v1 = *(const f16x8*)(vr + c1 * 8);
        oA[ni] = __builtin_amdgcn_mfma_f32_16x16x32_f16(pA0, v0, oA[ni], 0, 0, 0);
        oA[ni] = __builtin_amdgcn_mfma_f32_16x16x32_f16(pA1, v1, oA[ni], 0, 0, 0);
      }
    }
  }

  // epilogue: reduce l across the 16 lanes of each quad-group, normalize, store
#pragma unroll
  for (int r = 0; r < 4; ++r) {
    float la = lA_[r], lb = lB_[r];
#pragma unroll
    for (int off = 1; off < 16; off <<= 1) {
      la += __shfl_xor(la, off, 64);
      lb += __shfl_xor(lb, off, 64);
    }
    const int rowA = qtA * 64 + wave * 16 + quad * 4 + r;
    const int rowB = qtB * 64 + wave * 16 + quad * 4 + r;
    float invA = 1.f / la;
    float invB = 1.f / lb;
#pragma unroll
    for (int ni = 0; ni < 4; ++ni) {
      O[(size_t)(b * T_ + rowA) * C_ + h * 64 + ni * 16 + lr] = (f16)(oA[ni][r] * invA);
      O[(size_t)(b * T_ + rowB) * C_ + h * 64 + ni * 16 + lr] = (f16)(oB[ni][r] * invB);
    }
  }
}

// ---------------- launch ----------------
extern "C" void kernel_launch(void* const* d_in, const int* in_sizes, int n_in,
                              void* d_out, int out_size, void* d_ws, size_t ws_size,
                              hipStream_t stream)
{
  const float* x    = (const float*)d_in[0];
  const float* Wqkv = (const float*)d_in[1];
  const float* bqkv = (const float*)d_in[2];
  const float* Wout = (const float*)d_in[3];
  const float* bout = (const float*)d_in[4];
  float* out = (float*)d_out;

  f16* xh    = (f16*)d_ws;                            // 8192*1024
  f16* WqkvT = xh + (size_t)8192 * 1024;              // 3072*1024
  f16* WoutT = WqkvT + (size_t)3072 * 1024;           // 1024*1024
  f16* QKV   = WoutT + (size_t)1024 * 1024;           // 8192*3072 (V region unused)
  f16* VtG   = QKV + (size_t)8192 * 3072;             // 64*64*2048
  f16* Oh    = VtG + (size_t)64 * 64 * 2048;          // 8192*1024

  k_prep<<<12288, 256, 0, stream>>>(x, xh, Wqkv, WqkvT, Wout, WoutT);

  // QKV projection; V columns go directly (transposed) to VtG
  k_gemm256<<<dim3(3072 / 128, 8192 / 256), 256, 0, stream>>>(
      xh, WqkvT, bqkv, QKV, VtG, 8192, 3072, 1024);

  k_flash<<<dim3(16, B_ * H_), 256, 0, stream>>>(QKV, VtG, Oh);

  // output projection -> f32 out
  k_gemm_bt<<<dim3(1024 / 128, 8192 / 128), 256, 0, stream>>>(
      Oh, WoutT, bout, out, 8192, 1024, 1024);
}